// Round 1
// baseline (190.426 us; speedup 1.0000x reference)
//
#include <hip/hip_runtime.h>
#include <stdint.h>

// Problem constants
#define NB 2
#define NS 2048
#define ND 1024
#define NH 16
#define NHD 64
#define SCALE_Q 0.125f

typedef __attribute__((ext_vector_type(8))) short bf16x8;
typedef __attribute__((ext_vector_type(4))) float f32x4;

__device__ __forceinline__ unsigned short f2bf(float f) {
  union { float f; unsigned u; } v; v.f = f;
  unsigned r = v.u + 0x7FFFu + ((v.u >> 16) & 1u);
  return (unsigned short)(r >> 16);
}

// async global->LDS, 16B per lane. Dest must be wave-uniform base (HW adds lane*16).
__device__ __forceinline__ void gload16(const void* g, void* l) {
  __builtin_amdgcn_global_load_lds(
      (const __attribute__((address_space(1))) unsigned int*)g,
      (__attribute__((address_space(3))) unsigned int*)l, 16, 0, 0);
}

// ---------------- convert kernels ----------------

// x f32 -> bf16, 8 elems/thread, exact grid
__global__ void cvt_x(const float* __restrict__ in, unsigned short* __restrict__ out) {
  int i = blockIdx.x * 256 + threadIdx.x;
  const float4* p = (const float4*)in + (size_t)i * 2;
  float4 a = p[0], b = p[1];
  typedef __attribute__((ext_vector_type(8))) unsigned short u16x8;
  u16x8 o;
  o[0] = f2bf(a.x); o[1] = f2bf(a.y); o[2] = f2bf(a.z); o[3] = f2bf(a.w);
  o[4] = f2bf(b.x); o[5] = f2bf(b.y); o[6] = f2bf(b.z); o[7] = f2bf(b.w);
  *((u16x8*)out + i) = o;
}

// W [rows][cols] f32 -> WT [cols][rows] bf16, 32x32 LDS tiles
__global__ void transpose_cvt(const float* __restrict__ W, unsigned short* __restrict__ WT,
                              int rows, int cols) {
  __shared__ float tile[32][33];
  int bc = blockIdx.x * 32;
  int br = blockIdx.y * 32;
  int tx = threadIdx.x & 31, ty = threadIdx.x >> 5;
#pragma unroll
  for (int i = 0; i < 4; ++i)
    tile[ty + i * 8][tx] = W[(size_t)(br + ty + i * 8) * cols + bc + tx];
  __syncthreads();
#pragma unroll
  for (int i = 0; i < 4; ++i)
    WT[(size_t)(bc + ty + i * 8) * rows + br + tx] = f2bf(tile[tx][ty + i * 8]);
}

// ---------------- GEMM: C[M,N] = A[M,K=1024] * Bt[N,K=1024]^T ----------------
// 128x128 tile, BK=64, 256 threads (4 waves, each 64x64), mfma 16x16x32 bf16.
// LDS XOR-swizzled (byte ^= (row&7)<<4) via pre-swizzled global source.
// EPI 0: QKV epilogue (bias, scatter Q*SCALE/K to [B,H,S,HD], V to Vt [B,H,HD,S])
// EPI 1: proj epilogue (bias, f32 out [M,N])
template <int EPI>
__global__ __launch_bounds__(256, 2) void gemm_bt(
    const unsigned short* __restrict__ A, const unsigned short* __restrict__ Bt,
    const float* __restrict__ bias, int NT,
    unsigned short* __restrict__ Oq, unsigned short* __restrict__ Ok,
    unsigned short* __restrict__ Ov, float* __restrict__ Of) {
  __shared__ __align__(16) unsigned short lA[128 * 64];
  __shared__ __align__(16) unsigned short lB[128 * 64];

  int bid = blockIdx.x;
  int cpx = gridDim.x >> 3;                       // grid % 8 == 0 (bijective XCD swizzle)
  int swz = (bid & 7) * cpx + (bid >> 3);
  int mt = swz / NT, nt = swz % NT;
  int m0 = mt * 128, n0 = nt * 128;

  int t = threadIdx.x, lane = t & 63, w = t >> 6;
  int wm = w >> 1, wn = w & 1;

  f32x4 acc[4][4] = {};

  const char* gA = (const char*)(A + (size_t)m0 * 1024);
  const char* gB = (const char*)(Bt + (size_t)n0 * 1024);

  for (int kt = 0; kt < 16; ++kt) {
    __syncthreads();
#pragma unroll
    for (int r = 0; r < 4; ++r) {
      int L = r * 4096 + w * 1024 + lane * 16;    // linear LDS byte
      int row = L >> 7, cb = L & 127;
      int scb = cb ^ ((row & 7) << 4);            // pre-swizzled source column
      gload16(gA + (size_t)row * 2048 + kt * 128 + scb, (char*)lA + (L - lane * 16));
      gload16(gB + (size_t)row * 2048 + kt * 128 + scb, (char*)lB + (L - lane * 16));
    }
    __syncthreads();
#pragma unroll
    for (int kk = 0; kk < 2; ++kk) {
      bf16x8 af[4], bg[4];
#pragma unroll
      for (int mi = 0; mi < 4; ++mi) {
        int row = wm * 64 + mi * 16 + (lane & 15);
        int byte = row * 128 + ((kk * 64 + (lane >> 4) * 16) ^ ((row & 7) << 4));
        af[mi] = *(const bf16x8*)((const char*)lA + byte);
      }
#pragma unroll
      for (int ni = 0; ni < 4; ++ni) {
        int row = wn * 64 + ni * 16 + (lane & 15);
        int byte = row * 128 + ((kk * 64 + (lane >> 4) * 16) ^ ((row & 7) << 4));
        bg[ni] = *(const bf16x8*)((const char*)lB + byte);
      }
#pragma unroll
      for (int mi = 0; mi < 4; ++mi)
#pragma unroll
        for (int ni = 0; ni < 4; ++ni)
          acc[mi][ni] = __builtin_amdgcn_mfma_f32_16x16x32_bf16(af[mi], bg[ni], acc[mi][ni], 0, 0, 0);
    }
  }

  // epilogue: D row=(lane>>4)*4+r, col=lane&15 (m89-verified layout)
#pragma unroll
  for (int mi = 0; mi < 4; ++mi)
#pragma unroll
    for (int ni = 0; ni < 4; ++ni) {
      int col = n0 + wn * 64 + ni * 16 + (lane & 15);
      float bv = bias[col];
#pragma unroll
      for (int r = 0; r < 4; ++r) {
        int row = m0 + wm * 64 + mi * 16 + (lane >> 4) * 4 + r;
        float v = acc[mi][ni][r] + bv;
        if (EPI == 0) {
          int which = col >> 10, dd = col & 1023;
          int h = dd >> 6, hd = dd & 63;
          int b = row >> 11, s = row & 2047;
          size_t bh = (size_t)(b * 16 + h);
          if (which == 0)      Oq[(bh * 2048 + s) * 64 + hd] = f2bf(v * SCALE_Q);
          else if (which == 1) Ok[(bh * 2048 + s) * 64 + hd] = f2bf(v);
          else                 Ov[(bh * 64 + hd) * 2048 + s] = f2bf(v);
        } else {
          Of[(size_t)row * 1024 + col] = v;
        }
      }
    }
}

// ---------------- causal flash attention ----------------
// grid (S/64, B*H), 256 threads = 4 waves, each wave 16 q-rows.
// Q pre-scaled. K tiles [64 kv][64 d], V^T tiles [64 d][64 kv] staged swizzled.
__global__ __launch_bounds__(256, 2) void attn_fwd(
    const unsigned short* __restrict__ Qb, const unsigned short* __restrict__ Kb,
    const unsigned short* __restrict__ Vt, unsigned short* __restrict__ Ao) {
  __shared__ __align__(16) unsigned short lK[64 * 64];
  __shared__ __align__(16) unsigned short lV[64 * 64];
  __shared__ __align__(16) unsigned short lP[4][16 * 72];  // per-wave P, stride 72 elems

  int qb = blockIdx.x, bh = blockIdx.y;
  int q0 = qb * 64;
  int t = threadIdx.x, lane = t & 63, w = t >> 6;

  // Q A-frags: row = lane&15 (within wave's 16 rows), k = (lane>>4)*8 + j
  const unsigned short* Qg = Qb + ((size_t)bh * 2048 + q0 + w * 16 + (lane & 15)) * 64;
  bf16x8 qf0 = *(const bf16x8*)(Qg + (lane >> 4) * 8);
  bf16x8 qf1 = *(const bf16x8*)(Qg + 32 + (lane >> 4) * 8);

  f32x4 o[4] = {};
  float m[4] = {-1e30f, -1e30f, -1e30f, -1e30f};
  float lsum[4] = {0.f, 0.f, 0.f, 0.f};

  const char* Kg = (const char*)(Kb + (size_t)bh * 2048 * 64);
  const char* Vg = (const char*)(Vt + (size_t)bh * 64 * 2048);

  int ntiles = qb + 1;
  for (int it = 0; it < ntiles; ++it) {
    int s0 = it * 64;
    __syncthreads();
#pragma unroll
    for (int r = 0; r < 2; ++r) {
      int L = r * 4096 + w * 1024 + lane * 16;
      int row = L >> 7, cb = L & 127;
      int scb = cb ^ ((row & 7) << 4);
      gload16(Kg + (size_t)(s0 + row) * 128 + scb, (char*)lK + (L - lane * 16));
      gload16(Vg + (size_t)row * 4096 + s0 * 2 + scb, (char*)lV + (L - lane * 16));
    }
    __syncthreads();

    // S = Q @ K^T  (B[d][kv]=K[kv][d] -> lane reads lK row ni*16+(lane&15), 8 contiguous d)
    f32x4 sv[4] = {};
#pragma unroll
    for (int ni = 0; ni < 4; ++ni) {
      int row = ni * 16 + (lane & 15);
      int base = row * 128, sw = (row & 7) << 4;
      bf16x8 k0 = *(const bf16x8*)((const char*)lK + base + (((lane >> 4) * 16) ^ sw));
      bf16x8 k1 = *(const bf16x8*)((const char*)lK + base + ((64 + (lane >> 4) * 16) ^ sw));
      sv[ni] = __builtin_amdgcn_mfma_f32_16x16x32_bf16(qf0, k0, sv[ni], 0, 0, 0);
      sv[ni] = __builtin_amdgcn_mfma_f32_16x16x32_bf16(qf1, k1, sv[ni], 0, 0, 0);
    }

    if (s0 == q0) {  // diagonal tile: mask kv > q
#pragma unroll
      for (int ni = 0; ni < 4; ++ni)
#pragma unroll
        for (int r = 0; r < 4; ++r) {
          int qit = w * 16 + (lane >> 4) * 4 + r;
          int kit = ni * 16 + (lane & 15);
          if (kit > qit) sv[ni][r] = -1e30f;
        }
    }

    // online softmax (rows live in 16-lane groups; xor-reduce masks 1,2,4,8)
    float rmax[4];
#pragma unroll
    for (int r = 0; r < 4; ++r)
      rmax[r] = fmaxf(fmaxf(sv[0][r], sv[1][r]), fmaxf(sv[2][r], sv[3][r]));
#pragma unroll
    for (int msk = 1; msk < 16; msk <<= 1)
#pragma unroll
      for (int r = 0; r < 4; ++r) rmax[r] = fmaxf(rmax[r], __shfl_xor(rmax[r], msk));

    float sf[4];
#pragma unroll
    for (int r = 0; r < 4; ++r) {
      float mn = fmaxf(m[r], rmax[r]);
      sf[r] = __expf(m[r] - mn);
      m[r] = mn;
    }
    float rsum[4] = {0.f, 0.f, 0.f, 0.f};
    unsigned short pw[4][4];
#pragma unroll
    for (int ni = 0; ni < 4; ++ni)
#pragma unroll
      for (int r = 0; r < 4; ++r) {
        float p = __expf(sv[ni][r] - m[r]);
        rsum[r] += p;
        pw[ni][r] = f2bf(p);
      }
#pragma unroll
    for (int msk = 1; msk < 16; msk <<= 1)
#pragma unroll
      for (int r = 0; r < 4; ++r) rsum[r] += __shfl_xor(rsum[r], msk);
#pragma unroll
    for (int r = 0; r < 4; ++r) lsum[r] = lsum[r] * sf[r] + rsum[r];
#pragma unroll
    for (int di = 0; di < 4; ++di)
#pragma unroll
      for (int r = 0; r < 4; ++r) o[di][r] *= sf[r];

    // P: D-layout -> A-layout via per-wave LDS (stride 72 elems = 2-way conflicts only)
    unsigned short* Pw = &lP[w][0];
#pragma unroll
    for (int ni = 0; ni < 4; ++ni)
#pragma unroll
      for (int r = 0; r < 4; ++r)
        Pw[((lane >> 4) * 4 + r) * 72 + ni * 16 + (lane & 15)] = pw[ni][r];
    bf16x8 pa0 = *(const bf16x8*)(Pw + (lane & 15) * 72 + (lane >> 4) * 8);
    bf16x8 pa1 = *(const bf16x8*)(Pw + (lane & 15) * 72 + 32 + (lane >> 4) * 8);

    // O += P @ V  (B[kv][d]=Vt[d][kv] -> lane reads lV row di*16+(lane&15), 8 contiguous kv)
#pragma unroll
    for (int di = 0; di < 4; ++di) {
      int row = di * 16 + (lane & 15);
      int base = row * 128, sw = (row & 7) << 4;
      bf16x8 v0 = *(const bf16x8*)((const char*)lV + base + (((lane >> 4) * 16) ^ sw));
      bf16x8 v1 = *(const bf16x8*)((const char*)lV + base + ((64 + (lane >> 4) * 16) ^ sw));
      o[di] = __builtin_amdgcn_mfma_f32_16x16x32_bf16(pa0, v0, o[di], 0, 0, 0);
      o[di] = __builtin_amdgcn_mfma_f32_16x16x32_bf16(pa1, v1, o[di], 0, 0, 0);
    }
  }

  int b = bh >> 4, h = bh & 15;
#pragma unroll
  for (int r = 0; r < 4; ++r) lsum[r] = 1.0f / lsum[r];
  int qrow = q0 + w * 16 + (lane >> 4) * 4;
#pragma unroll
  for (int di = 0; di < 4; ++di)
#pragma unroll
    for (int r = 0; r < 4; ++r) {
      float v = o[di][r] * lsum[r];
      Ao[(size_t)(b * 2048 + qrow + r) * 1024 + h * 64 + di * 16 + (lane & 15)] = f2bf(v);
    }
}

// ---------------- launcher ----------------
extern "C" void kernel_launch(void* const* d_in, const int* in_sizes, int n_in,
                              void* d_out, int out_size, void* d_ws, size_t ws_size,
                              hipStream_t stream) {
  const float* x      = (const float*)d_in[0];
  const float* W_qkv  = (const float*)d_in[1];
  const float* b_qkv  = (const float*)d_in[2];
  const float* W_proj = (const float*)d_in[3];
  const float* b_proj = (const float*)d_in[4];
  float* out = (float*)d_out;

  char* ws = (char*)d_ws;
  const size_t MB = 1u << 20;
  unsigned short* xb     = (unsigned short*)(ws);            // 8 MB (reused as attn out)
  unsigned short* WqkvT  = (unsigned short*)(ws + 8 * MB);   // 6 MB
  unsigned short* WprojT = (unsigned short*)(ws + 14 * MB);  // 2 MB
  unsigned short* Qb     = (unsigned short*)(ws + 16 * MB);  // 8 MB
  unsigned short* Kb     = (unsigned short*)(ws + 24 * MB);  // 8 MB
  unsigned short* Vt     = (unsigned short*)(ws + 32 * MB);  // 8 MB
  unsigned short* attn   = xb;                               // alias: xb dead after QKV GEMM

  cvt_x<<<2048, 256, 0, stream>>>(x, xb);                       // 4M elems, 8/thread
  transpose_cvt<<<dim3(96, 32), 256, 0, stream>>>(W_qkv, WqkvT, 1024, 3072);
  transpose_cvt<<<dim3(32, 32), 256, 0, stream>>>(W_proj, WprojT, 1024, 1024);
  gemm_bt<0><<<768, 256, 0, stream>>>(xb, WqkvT, b_qkv, 24, Qb, Kb, Vt, nullptr);
  attn_fwd<<<dim3(32, 32), 256, 0, stream>>>(Qb, Kb, Vt, attn);
  gemm_bt<1><<<256, 256, 0, stream>>>(attn, WprojT, b_proj, 8, nullptr, nullptr, nullptr, out);
}

// Round 2
// 145.477 us; speedup vs baseline: 1.3090x; 1.3090x over previous
//
#include <hip/hip_runtime.h>
#include <stdint.h>

// Problem constants
#define NB 2
#define NS 2048
#define ND 1024
#define NH 16
#define NHD 64
#define SCALE_Q 0.125f

typedef __attribute__((ext_vector_type(8))) short bf16x8;
typedef __attribute__((ext_vector_type(4))) float f32x4;

__device__ __forceinline__ unsigned short f2bf(float f) {
  union { float f; unsigned u; } v; v.f = f;
  unsigned r = v.u + 0x7FFFu + ((v.u >> 16) & 1u);
  return (unsigned short)(r >> 16);
}

// async global->LDS, 16B per lane. Dest must be wave-uniform base (HW adds lane*16).
__device__ __forceinline__ void gload16(const void* g, void* l) {
  __builtin_amdgcn_global_load_lds(
      (const __attribute__((address_space(1))) unsigned int*)g,
      (__attribute__((address_space(3))) unsigned int*)l, 16, 0, 0);
}

// ---------------- convert kernels ----------------

// x f32 -> bf16, 8 elems/thread, exact grid
__global__ void cvt_x(const float* __restrict__ in, unsigned short* __restrict__ out) {
  int i = blockIdx.x * 256 + threadIdx.x;
  const float4* p = (const float4*)in + (size_t)i * 2;
  float4 a = p[0], b = p[1];
  typedef __attribute__((ext_vector_type(8))) unsigned short u16x8;
  u16x8 o;
  o[0] = f2bf(a.x); o[1] = f2bf(a.y); o[2] = f2bf(a.z); o[3] = f2bf(a.w);
  o[4] = f2bf(b.x); o[5] = f2bf(b.y); o[6] = f2bf(b.z); o[7] = f2bf(b.w);
  *((u16x8*)out + i) = o;
}

// W [rows][cols] f32 -> WT [cols][rows] bf16, 32x32 LDS tiles
__global__ void transpose_cvt(const float* __restrict__ W, unsigned short* __restrict__ WT,
                              int rows, int cols) {
  __shared__ float tile[32][33];
  int bc = blockIdx.x * 32;
  int br = blockIdx.y * 32;
  int tx = threadIdx.x & 31, ty = threadIdx.x >> 5;
#pragma unroll
  for (int i = 0; i < 4; ++i)
    tile[ty + i * 8][tx] = W[(size_t)(br + ty + i * 8) * cols + bc + tx];
  __syncthreads();
#pragma unroll
  for (int i = 0; i < 4; ++i)
    WT[(size_t)(bc + ty + i * 8) * rows + br + tx] = f2bf(tile[tx][ty + i * 8]);
}

// ---------------- GEMM: C[M,N] = A[M,K=1024] * Bt[N,K=1024]^T ----------------
// 128x128 tile, BK=64, 256 threads (4 waves, each 64x64), mfma 16x16x32 bf16.
// LDS XOR-swizzled (byte ^= (row&7)<<4) via pre-swizzled global source.
// EPI 0: QKV epilogue (bias, scatter Q*SCALE/K to [B,H,S,HD], V to Vt [B,H,HD,S])
// EPI 1: proj epilogue (bias, f32 out [M,N])
template <int EPI>
__global__ __launch_bounds__(256, 2) void gemm_bt(
    const unsigned short* __restrict__ A, const unsigned short* __restrict__ Bt,
    const float* __restrict__ bias, int NT,
    unsigned short* __restrict__ Oq, unsigned short* __restrict__ Ok,
    unsigned short* __restrict__ Ov, float* __restrict__ Of) {
  __shared__ __align__(16) unsigned short lA[128 * 64];
  __shared__ __align__(16) unsigned short lB[128 * 64];

  int bid = blockIdx.x;
  int cpx = gridDim.x >> 3;                       // grid % 8 == 0 (bijective XCD swizzle)
  int swz = (bid & 7) * cpx + (bid >> 3);
  int mt = swz / NT, nt = swz % NT;
  int m0 = mt * 128, n0 = nt * 128;

  int t = threadIdx.x, lane = t & 63, w = t >> 6;
  int wm = w >> 1, wn = w & 1;

  f32x4 acc[4][4] = {};

  const char* gA = (const char*)(A + (size_t)m0 * 1024);
  const char* gB = (const char*)(Bt + (size_t)n0 * 1024);

  for (int kt = 0; kt < 16; ++kt) {
    __syncthreads();
#pragma unroll
    for (int r = 0; r < 4; ++r) {
      int L = r * 4096 + w * 1024 + lane * 16;    // linear LDS byte
      int row = L >> 7, cb = L & 127;
      int scb = cb ^ ((row & 7) << 4);            // pre-swizzled source column
      gload16(gA + (size_t)row * 2048 + kt * 128 + scb, (char*)lA + (L - lane * 16));
      gload16(gB + (size_t)row * 2048 + kt * 128 + scb, (char*)lB + (L - lane * 16));
    }
    __syncthreads();
#pragma unroll
    for (int kk = 0; kk < 2; ++kk) {
      bf16x8 af[4], bg[4];
#pragma unroll
      for (int mi = 0; mi < 4; ++mi) {
        int row = wm * 64 + mi * 16 + (lane & 15);
        int byte = row * 128 + ((kk * 64 + (lane >> 4) * 16) ^ ((row & 7) << 4));
        af[mi] = *(const bf16x8*)((const char*)lA + byte);
      }
#pragma unroll
      for (int ni = 0; ni < 4; ++ni) {
        int row = wn * 64 + ni * 16 + (lane & 15);
        int byte = row * 128 + ((kk * 64 + (lane >> 4) * 16) ^ ((row & 7) << 4));
        bg[ni] = *(const bf16x8*)((const char*)lB + byte);
      }
#pragma unroll
      for (int mi = 0; mi < 4; ++mi)
#pragma unroll
        for (int ni = 0; ni < 4; ++ni)
          acc[mi][ni] = __builtin_amdgcn_mfma_f32_16x16x32_bf16(af[mi], bg[ni], acc[mi][ni], 0, 0, 0);
    }
  }

  // epilogue: D row=(lane>>4)*4+r, col=lane&15 (m89-verified layout)
#pragma unroll
  for (int mi = 0; mi < 4; ++mi)
#pragma unroll
    for (int ni = 0; ni < 4; ++ni) {
      int col = n0 + wn * 64 + ni * 16 + (lane & 15);
      float bv = bias[col];
#pragma unroll
      for (int r = 0; r < 4; ++r) {
        int row = m0 + wm * 64 + mi * 16 + (lane >> 4) * 4 + r;
        float v = acc[mi][ni][r] + bv;
        if (EPI == 0) {
          int which = col >> 10, dd = col & 1023;
          int h = dd >> 6, hd = dd & 63;
          int b = row >> 11, s = row & 2047;
          size_t bh = (size_t)(b * 16 + h);
          if (which == 0)      Oq[(bh * 2048 + s) * 64 + hd] = f2bf(v * SCALE_Q);
          else if (which == 1) Ok[(bh * 2048 + s) * 64 + hd] = f2bf(v);
          else                 Ov[(bh * 64 + hd) * 2048 + s] = f2bf(v);
        } else {
          Of[(size_t)row * 1024 + col] = v;
        }
      }
    }
}

// ---------------- causal flash attention ----------------
// Flat grid 1024 blocks: id = (31-qt)*32 + bh  -> heavy diagonal blocks dispatch
// first (dynamic load balance of causal work), and id%8 == bh%8 keeps each
// head's K/V on one XCD's L2. 4 waves/block, 16 q-rows/wave, KVBLK=64.
// Double-buffered K/V staging: STAGE(next) issued BEFORE compute, ONE barrier
// per tile (loads drain at the barrier after covering compute latency).
__global__ __launch_bounds__(256, 3) void attn_fwd(
    const unsigned short* __restrict__ Qb, const unsigned short* __restrict__ Kb,
    const unsigned short* __restrict__ Vt, unsigned short* __restrict__ Ao) {
  __shared__ __align__(16) unsigned short lK[2][64 * 64];
  __shared__ __align__(16) unsigned short lV[2][64 * 64];
  __shared__ __align__(16) unsigned short lP[4][16 * 72];  // per-wave P, stride 72 elems

  int id = blockIdx.x;
  int qt = 31 - (id >> 5);   // heavy-first
  int bh = id & 31;          // id%8 == bh%8 (XCD affinity)
  int q0 = qt * 64;
  int t = threadIdx.x, lane = t & 63, w = t >> 6;

  // Q A-frags: row = lane&15 (within wave's 16 rows), k = (lane>>4)*8 + j
  const unsigned short* Qg = Qb + ((size_t)bh * 2048 + q0 + w * 16 + (lane & 15)) * 64;
  bf16x8 qf0 = *(const bf16x8*)(Qg + (lane >> 4) * 8);
  bf16x8 qf1 = *(const bf16x8*)(Qg + 32 + (lane >> 4) * 8);

  f32x4 o[4] = {};
  float m[4] = {-1e30f, -1e30f, -1e30f, -1e30f};
  float lsum[4] = {0.f, 0.f, 0.f, 0.f};

  const char* Kg = (const char*)(Kb + (size_t)bh * 2048 * 64);
  const char* Vg = (const char*)(Vt + (size_t)bh * 64 * 2048);

  int Lb = w * 1024 + lane * 16;
  auto STAGE = [&](int buf, int tile) {
    int s0 = tile * 64;
#pragma unroll
    for (int r = 0; r < 2; ++r) {
      int L = r * 4096 + Lb;
      int row = L >> 7, cb = L & 127;
      int scb = cb ^ ((row & 7) << 4);
      gload16(Kg + (size_t)(s0 + row) * 128 + scb, (char*)&lK[buf][0] + (L - lane * 16));
      gload16(Vg + (size_t)row * 4096 + (size_t)s0 * 2 + scb, (char*)&lV[buf][0] + (L - lane * 16));
    }
  };

  int ntiles = qt + 1;
  STAGE(0, 0);
  __syncthreads();   // drains prologue staging

  int cur = 0;
  for (int it = 0; it < ntiles; ++it) {
    if (it + 1 < ntiles) STAGE(cur ^ 1, it + 1);   // prefetch next tile (overlaps compute)

    const char* bK = (const char*)&lK[cur][0];
    const char* bV = (const char*)&lV[cur][0];

    // S = Q @ K^T  (B[d][kv]=K[kv][d] -> lane reads lK row ni*16+(lane&15), 8 contiguous d)
    f32x4 sv[4] = {};
    __builtin_amdgcn_s_setprio(1);
#pragma unroll
    for (int ni = 0; ni < 4; ++ni) {
      int row = ni * 16 + (lane & 15);
      int base = row * 128, sw = (row & 7) << 4;
      bf16x8 k0 = *(const bf16x8*)(bK + base + (((lane >> 4) * 16) ^ sw));
      bf16x8 k1 = *(const bf16x8*)(bK + base + ((64 + (lane >> 4) * 16) ^ sw));
      sv[ni] = __builtin_amdgcn_mfma_f32_16x16x32_bf16(qf0, k0, sv[ni], 0, 0, 0);
      sv[ni] = __builtin_amdgcn_mfma_f32_16x16x32_bf16(qf1, k1, sv[ni], 0, 0, 0);
    }
    __builtin_amdgcn_s_setprio(0);

    if (it == ntiles - 1) {  // diagonal tile: mask kv > q
#pragma unroll
      for (int ni = 0; ni < 4; ++ni)
#pragma unroll
        for (int r = 0; r < 4; ++r) {
          int qit = w * 16 + (lane >> 4) * 4 + r;
          int kit = ni * 16 + (lane & 15);
          if (kit > qit) sv[ni][r] = -1e30f;
        }
    }

    // online softmax (rows live in 16-lane groups; xor-reduce masks 1,2,4,8)
    float rmax[4];
#pragma unroll
    for (int r = 0; r < 4; ++r)
      rmax[r] = fmaxf(fmaxf(sv[0][r], sv[1][r]), fmaxf(sv[2][r], sv[3][r]));
#pragma unroll
    for (int msk = 1; msk < 16; msk <<= 1)
#pragma unroll
      for (int r = 0; r < 4; ++r) rmax[r] = fmaxf(rmax[r], __shfl_xor(rmax[r], msk));

    // T13 defer-max: skip O/lsum rescale while max growth <= 8 (wave-uniform branch)
    int defer = __all(rmax[0] <= m[0] + 8.0f && rmax[1] <= m[1] + 8.0f &&
                      rmax[2] <= m[2] + 8.0f && rmax[3] <= m[3] + 8.0f);
    if (!defer) {
#pragma unroll
      for (int r = 0; r < 4; ++r) {
        float mn = fmaxf(m[r], rmax[r]);
        float sf = __expf(m[r] - mn);
        m[r] = mn;
        lsum[r] *= sf;
#pragma unroll
        for (int di = 0; di < 4; ++di) o[di][r] *= sf;
      }
    }

    float rsum[4] = {0.f, 0.f, 0.f, 0.f};
    unsigned short pw[4][4];
#pragma unroll
    for (int ni = 0; ni < 4; ++ni)
#pragma unroll
      for (int r = 0; r < 4; ++r) {
        float p = __expf(sv[ni][r] - m[r]);
        rsum[r] += p;
        pw[ni][r] = f2bf(p);
      }
#pragma unroll
    for (int msk = 1; msk < 16; msk <<= 1)
#pragma unroll
      for (int r = 0; r < 4; ++r) rsum[r] += __shfl_xor(rsum[r], msk);
#pragma unroll
    for (int r = 0; r < 4; ++r) lsum[r] += rsum[r];

    // P: D-layout -> A-layout via per-wave LDS (stride 72 elems = 2-way conflicts only)
    unsigned short* Pw = &lP[w][0];
#pragma unroll
    for (int ni = 0; ni < 4; ++ni)
#pragma unroll
      for (int r = 0; r < 4; ++r)
        Pw[((lane >> 4) * 4 + r) * 72 + ni * 16 + (lane & 15)] = pw[ni][r];
    bf16x8 pa0 = *(const bf16x8*)(Pw + (lane & 15) * 72 + (lane >> 4) * 8);
    bf16x8 pa1 = *(const bf16x8*)(Pw + (lane & 15) * 72 + 32 + (lane >> 4) * 8);

    // O += P @ V  (B[kv][d]=Vt[d][kv] -> lane reads lV row di*16+(lane&15), 8 contiguous kv)
    __builtin_amdgcn_s_setprio(1);
#pragma unroll
    for (int di = 0; di < 4; ++di) {
      int row = di * 16 + (lane & 15);
      int base = row * 128, sw = (row & 7) << 4;
      bf16x8 v0 = *(const bf16x8*)(bV + base + (((lane >> 4) * 16) ^ sw));
      bf16x8 v1 = *(const bf16x8*)(bV + base + ((64 + (lane >> 4) * 16) ^ sw));
      o[di] = __builtin_amdgcn_mfma_f32_16x16x32_bf16(pa0, v0, o[di], 0, 0, 0);
      o[di] = __builtin_amdgcn_mfma_f32_16x16x32_bf16(pa1, v1, o[di], 0, 0, 0);
    }
    __builtin_amdgcn_s_setprio(0);

    __syncthreads();   // staged tile it+1 complete; all waves done with buf cur
    cur ^= 1;
  }

  int b = bh >> 4, h = bh & 15;
#pragma unroll
  for (int r = 0; r < 4; ++r) lsum[r] = 1.0f / lsum[r];
  int qrow = q0 + w * 16 + (lane >> 4) * 4;
#pragma unroll
  for (int di = 0; di < 4; ++di)
#pragma unroll
    for (int r = 0; r < 4; ++r) {
      float v = o[di][r] * lsum[r];
      Ao[(size_t)(b * 2048 + qrow + r) * 1024 + h * 64 + di * 16 + (lane & 15)] = f2bf(v);
    }
}

// ---------------- launcher ----------------
extern "C" void kernel_launch(void* const* d_in, const int* in_sizes, int n_in,
                              void* d_out, int out_size, void* d_ws, size_t ws_size,
                              hipStream_t stream) {
  const float* x      = (const float*)d_in[0];
  const float* W_qkv  = (const float*)d_in[1];
  const float* b_qkv  = (const float*)d_in[2];
  const float* W_proj = (const float*)d_in[3];
  const float* b_proj = (const float*)d_in[4];
  float* out = (float*)d_out;

  char* ws = (char*)d_ws;
  const size_t MB = 1u << 20;
  unsigned short* xb     = (unsigned short*)(ws);            // 8 MB (reused as attn out)
  unsigned short* WqkvT  = (unsigned short*)(ws + 8 * MB);   // 6 MB
  unsigned short* WprojT = (unsigned short*)(ws + 14 * MB);  // 2 MB
  unsigned short* Qb     = (unsigned short*)(ws + 16 * MB);  // 8 MB
  unsigned short* Kb     = (unsigned short*)(ws + 24 * MB);  // 8 MB
  unsigned short* Vt     = (unsigned short*)(ws + 32 * MB);  // 8 MB
  unsigned short* attn   = xb;                               // alias: xb dead after QKV GEMM

  cvt_x<<<2048, 256, 0, stream>>>(x, xb);                       // 4M elems, 8/thread
  transpose_cvt<<<dim3(96, 32), 256, 0, stream>>>(W_qkv, WqkvT, 1024, 3072);
  transpose_cvt<<<dim3(32, 32), 256, 0, stream>>>(W_proj, WprojT, 1024, 1024);
  gemm_bt<0><<<768, 256, 0, stream>>>(xb, WqkvT, b_qkv, 24, Qb, Kb, Vt, nullptr);
  attn_fwd<<<1024, 256, 0, stream>>>(Qb, Kb, Vt, attn);
  gemm_bt<1><<<256, 256, 0, stream>>>(attn, WprojT, b_proj, 8, nullptr, nullptr, nullptr, out);
}

// Round 3
// 127.591 us; speedup vs baseline: 1.4925x; 1.1402x over previous
//
#include <hip/hip_runtime.h>
#include <stdint.h>

// Problem constants
#define NB 2
#define NS 2048
#define ND 1024
#define NH 16
#define NHD 64
#define SCALE_QL2 0.1803368801111244f  // (1/sqrt(64)) * log2(e): attention runs in exp2 domain

typedef __attribute__((ext_vector_type(8))) short bf16x8;
typedef __attribute__((ext_vector_type(4))) float f32x4;
typedef __attribute__((ext_vector_type(16))) float f32x16;

__device__ __forceinline__ unsigned short f2bf(float f) {
  union { float f; unsigned u; } v; v.f = f;
  unsigned r = v.u + 0x7FFFu + ((v.u >> 16) & 1u);
  return (unsigned short)(r >> 16);
}

__device__ __forceinline__ float fexp2(float x) { return __builtin_amdgcn_exp2f(x); }

// pack 2 f32 -> 1 u32 of 2 bf16 (lo = a, hi = b), RNE
__device__ __forceinline__ unsigned cvtpk(float a, float b) {
  unsigned r;
  asm("v_cvt_pk_bf16_f32 %0, %1, %2" : "=v"(r) : "v"(a), "v"(b));
  return r;
}

// cross-half exchange: a' = [a_lo32lanes, b_lo32lanes], b' = [a_hi32lanes, b_hi32lanes]
__device__ __forceinline__ void plswap(unsigned& a, unsigned& b) {
  asm("v_permlane32_swap_b32 %0, %1" : "+v"(a), "+v"(b));
}

// async global->LDS, 16B per lane. Dest must be wave-uniform base (HW adds lane*16).
__device__ __forceinline__ void gload16(const void* g, void* l) {
  __builtin_amdgcn_global_load_lds(
      (const __attribute__((address_space(1))) unsigned int*)g,
      (__attribute__((address_space(3))) unsigned int*)l, 16, 0, 0);
}

// ---------------- convert kernels ----------------

__global__ void cvt_x(const float* __restrict__ in, unsigned short* __restrict__ out) {
  int i = blockIdx.x * 256 + threadIdx.x;
  const float4* p = (const float4*)in + (size_t)i * 2;
  float4 a = p[0], b = p[1];
  typedef __attribute__((ext_vector_type(8))) unsigned short u16x8;
  u16x8 o;
  o[0] = f2bf(a.x); o[1] = f2bf(a.y); o[2] = f2bf(a.z); o[3] = f2bf(a.w);
  o[4] = f2bf(b.x); o[5] = f2bf(b.y); o[6] = f2bf(b.z); o[7] = f2bf(b.w);
  *((u16x8*)out + i) = o;
}

__global__ void transpose_cvt(const float* __restrict__ W, unsigned short* __restrict__ WT,
                              int rows, int cols) {
  __shared__ float tile[32][33];
  int bc = blockIdx.x * 32;
  int br = blockIdx.y * 32;
  int tx = threadIdx.x & 31, ty = threadIdx.x >> 5;
#pragma unroll
  for (int i = 0; i < 4; ++i)
    tile[ty + i * 8][tx] = W[(size_t)(br + ty + i * 8) * cols + bc + tx];
  __syncthreads();
#pragma unroll
  for (int i = 0; i < 4; ++i)
    WT[(size_t)(bc + ty + i * 8) * rows + br + tx] = f2bf(tile[tx][ty + i * 8]);
}

// ---------------- GEMM: C[M,N] = A[M,K=1024] * Bt[N,K=1024]^T ----------------
template <int EPI>
__global__ __launch_bounds__(256, 2) void gemm_bt(
    const unsigned short* __restrict__ A, const unsigned short* __restrict__ Bt,
    const float* __restrict__ bias, int NT,
    unsigned short* __restrict__ Oq, unsigned short* __restrict__ Ok,
    unsigned short* __restrict__ Ov, float* __restrict__ Of) {
  __shared__ __align__(16) unsigned short lA[128 * 64];
  __shared__ __align__(16) unsigned short lB[128 * 64];

  int bid = blockIdx.x;
  int cpx = gridDim.x >> 3;
  int swz = (bid & 7) * cpx + (bid >> 3);
  int mt = swz / NT, nt = swz % NT;
  int m0 = mt * 128, n0 = nt * 128;

  int t = threadIdx.x, lane = t & 63, w = t >> 6;
  int wm = w >> 1, wn = w & 1;

  f32x4 acc[4][4] = {};

  const char* gA = (const char*)(A + (size_t)m0 * 1024);
  const char* gB = (const char*)(Bt + (size_t)n0 * 1024);

  for (int kt = 0; kt < 16; ++kt) {
    __syncthreads();
#pragma unroll
    for (int r = 0; r < 4; ++r) {
      int L = r * 4096 + w * 1024 + lane * 16;
      int row = L >> 7, cb = L & 127;
      int scb = cb ^ ((row & 7) << 4);
      gload16(gA + (size_t)row * 2048 + kt * 128 + scb, (char*)lA + (L - lane * 16));
      gload16(gB + (size_t)row * 2048 + kt * 128 + scb, (char*)lB + (L - lane * 16));
    }
    __syncthreads();
#pragma unroll
    for (int kk = 0; kk < 2; ++kk) {
      bf16x8 af[4], bg[4];
#pragma unroll
      for (int mi = 0; mi < 4; ++mi) {
        int row = wm * 64 + mi * 16 + (lane & 15);
        int byte = row * 128 + ((kk * 64 + (lane >> 4) * 16) ^ ((row & 7) << 4));
        af[mi] = *(const bf16x8*)((const char*)lA + byte);
      }
#pragma unroll
      for (int ni = 0; ni < 4; ++ni) {
        int row = wn * 64 + ni * 16 + (lane & 15);
        int byte = row * 128 + ((kk * 64 + (lane >> 4) * 16) ^ ((row & 7) << 4));
        bg[ni] = *(const bf16x8*)((const char*)lB + byte);
      }
#pragma unroll
      for (int mi = 0; mi < 4; ++mi)
#pragma unroll
        for (int ni = 0; ni < 4; ++ni)
          acc[mi][ni] = __builtin_amdgcn_mfma_f32_16x16x32_bf16(af[mi], bg[ni], acc[mi][ni], 0, 0, 0);
    }
  }

#pragma unroll
  for (int mi = 0; mi < 4; ++mi)
#pragma unroll
    for (int ni = 0; ni < 4; ++ni) {
      int col = n0 + wn * 64 + ni * 16 + (lane & 15);
      float bv = bias[col];
#pragma unroll
      for (int r = 0; r < 4; ++r) {
        int row = m0 + wm * 64 + mi * 16 + (lane >> 4) * 4 + r;
        float v = acc[mi][ni][r] + bv;
        if (EPI == 0) {
          int which = col >> 10, dd = col & 1023;
          int h = dd >> 6, hd = dd & 63;
          int b = row >> 11, s = row & 2047;
          size_t bh = (size_t)(b * 16 + h);
          if (which == 0)      Oq[(bh * 2048 + s) * 64 + hd] = f2bf(v * SCALE_QL2);
          else if (which == 1) Ok[(bh * 2048 + s) * 64 + hd] = f2bf(v);
          else                 Ov[(bh * 64 + hd) * 2048 + s] = f2bf(v);
        } else {
          Of[(size_t)row * 1024 + col] = v;
        }
      }
    }
}

// ---------------- causal flash attention (swapped-QK^T, 32x32x16, in-reg softmax) ----------------
// grid 512: qt = id<256 ? 15-(id>>5) : (id>>5)-8  (heavy+light pairing per CU),
// bh = id&31 (id%8==bh%8 -> XCD L2 affinity). 4 waves x 32 q-rows = QBLK 128, KVBLK 64.
// S^T = mfma(K_frag, Q_frag): lane owns q = (lane&31); kv per reg r: (r&3)+8*(r>>2)+4*(lane>>5)+32h.
// Softmax fully in-register (per-lane chain + one shfl_xor(32)); P -> A-frag via cvt_pk + permlane32_swap.
__global__ __launch_bounds__(256, 3) void attn_fwd(
    const unsigned short* __restrict__ Qb, const unsigned short* __restrict__ Kb,
    const unsigned short* __restrict__ Vt, unsigned short* __restrict__ Ao) {
  __shared__ __align__(16) unsigned short lK[2][64 * 64];
  __shared__ __align__(16) unsigned short lV[2][64 * 64];

  int id = blockIdx.x;
  int g5 = id >> 5;
  int qt = (id < 256) ? (15 - g5) : (g5 - 8);
  int bh = id & 31;
  int t = threadIdx.x, lane = t & 63, w = t >> 6;
  int lo = lane & 31, hi = lane >> 5;
  int q0w = qt * 128 + w * 32;
  int swz = (lo & 7) << 4;

  // Q frags: q = q0w + lo, d = 16*kk + 8*hi + j (Q pre-scaled by SCALE*log2e)
  const unsigned short* Qg = Qb + ((size_t)bh * 2048 + q0w + lo) * 64 + hi * 8;
  bf16x8 qf[4];
#pragma unroll
  for (int kk = 0; kk < 4; ++kk) qf[kk] = *(const bf16x8*)(Qg + kk * 16);

  f32x16 o0 = {}, o1 = {};          // O[q=crow(r,hi)][d = 32*dh + lo]
  float m = -1e30f, lsum = 0.f;     // per-lane, for q = lo (duplicated across halves)

  const char* Kg = (const char*)(Kb + (size_t)bh * 2048 * 64);
  const char* Vg = (const char*)(Vt + (size_t)bh * 64 * 2048);

  int Lb = w * 1024 + lane * 16;
  auto STAGE = [&](int buf, int tile) {
    int s0 = tile * 64;
#pragma unroll
    for (int r = 0; r < 2; ++r) {
      int L = r * 4096 + Lb;
      int row = L >> 7, cb = L & 127;
      int scb = cb ^ ((row & 7) << 4);
      gload16(Kg + (size_t)(s0 + row) * 128 + scb, (char*)&lK[buf][0] + (L - lane * 16));
      gload16(Vg + (size_t)row * 4096 + (size_t)s0 * 2 + scb, (char*)&lV[buf][0] + (L - lane * 16));
    }
  };

  int ntiles = 2 * qt + 2;
  int itmax = 2 * qt + (w >> 1);    // last tile this wave's q-rows can see
  STAGE(0, 0);
  __syncthreads();

  int cur = 0;
  for (int it = 0; it < ntiles; ++it) {
    if (it + 1 < ntiles) STAGE(cur ^ 1, it + 1);
    if (it <= itmax) {
      const char* bK = (const char*)&lK[cur][0];
      const char* bV = (const char*)&lV[cur][0];

      // S^T: A = K rows (kv), B = Q. sv0: kv 0..31, sv1: kv 32..63 of tile.
      f32x16 sv0 = {}, sv1 = {};
      __builtin_amdgcn_s_setprio(1);
#pragma unroll
      for (int kk = 0; kk < 4; ++kk) {
        int dby = 32 * kk + 16 * hi;
        bf16x8 k0 = *(const bf16x8*)(bK + lo * 128 + (dby ^ swz));
        bf16x8 k1 = *(const bf16x8*)(bK + (32 + lo) * 128 + (dby ^ swz));
        sv0 = __builtin_amdgcn_mfma_f32_32x32x16_bf16(k0, qf[kk], sv0, 0, 0, 0);
        sv1 = __builtin_amdgcn_mfma_f32_32x32x16_bf16(k1, qf[kk], sv1, 0, 0, 0);
      }
      __builtin_amdgcn_s_setprio(0);

      if (it == itmax) {            // diagonal tile: mask kv > q
        int qg = q0w + lo, s0 = it * 64;
#pragma unroll
        for (int r = 0; r < 16; ++r) {
          int kv = s0 + (r & 3) + 8 * (r >> 2) + 4 * hi;
          if (kv > qg) sv0[r] = -1e30f;
          if (kv + 32 > qg) sv1[r] = -1e30f;
        }
      }

      // row max: per-lane chain over 32 regs + cross-half combine
      float rmax = -1e30f;
#pragma unroll
      for (int r = 0; r < 16; ++r) rmax = fmaxf(rmax, fmaxf(sv0[r], sv1[r]));
      rmax = fmaxf(rmax, __shfl_xor(rmax, 32));

      // T13 defer-max (exp2 domain, THR=8 -> p <= 256)
      if (__any(rmax > m + 8.0f)) {
        float mn = fmaxf(m, rmax);
        float sf = fexp2(m - mn);
        m = mn; lsum *= sf;
#pragma unroll
        for (int r = 0; r < 16; ++r) {
          float s = __shfl(sf, (r & 3) + 8 * (r >> 2) + 4 * hi);  // sf of O-row's q
          o0[r] *= s; o1[r] *= s;
        }
      }

      // p = 2^(s-m), row sum
      float rsum = 0.f;
#pragma unroll
      for (int r = 0; r < 16; ++r) {
        sv0[r] = fexp2(sv0[r] - m); rsum += sv0[r];
        sv1[r] = fexp2(sv1[r] - m); rsum += sv1[r];
      }
      rsum += __shfl_xor(rsum, 32);
      lsum += rsum;

      // P (D-layout) -> A-frags via cvt_pk + permlane32_swap (T12)
      bf16x8 pa[4];
#pragma unroll
      for (int h2 = 0; h2 < 2; ++h2) {
        const f32x16& P = h2 ? sv1 : sv0;
#pragma unroll
        for (int kp = 0; kp < 2; ++kp) {
          unsigned a0 = cvtpk(P[8 * kp + 0], P[8 * kp + 1]);
          unsigned a1 = cvtpk(P[8 * kp + 2], P[8 * kp + 3]);
          unsigned b0 = cvtpk(P[8 * kp + 4], P[8 * kp + 5]);
          unsigned b1 = cvtpk(P[8 * kp + 6], P[8 * kp + 7]);
          plswap(a0, b0); plswap(a1, b1);
          union { unsigned u[4]; bf16x8 v; } uu;
          uu.u[0] = a0; uu.u[1] = a1; uu.u[2] = b0; uu.u[3] = b1;
          pa[2 * h2 + kp] = uu.v;
        }
      }

      // O += P @ V: A = pa[ks] (q x kv16), B = V[kv][d] read from Vt rows
      __builtin_amdgcn_s_setprio(1);
#pragma unroll
      for (int dh = 0; dh < 2; ++dh) {
        f32x16& oc = dh ? o1 : o0;
#pragma unroll
        for (int ks = 0; ks < 4; ++ks) {
          int kvby = 32 * ks + 16 * hi;
          bf16x8 vf = *(const bf16x8*)(bV + (32 * dh + lo) * 128 + (kvby ^ swz));
          oc = __builtin_amdgcn_mfma_f32_32x32x16_bf16(pa[ks], vf, oc, 0, 0, 0);
        }
      }
      __builtin_amdgcn_s_setprio(0);
    }
    __syncthreads();
    cur ^= 1;
  }

  // epilogue: normalize by 1/lsum (broadcast to O-rows) and store
  float rl = 1.0f / lsum;
  int b = bh >> 4, hh = bh & 15;
#pragma unroll
  for (int r = 0; r < 16; ++r) {
    int qrow = (r & 3) + 8 * (r >> 2) + 4 * hi;
    float s = __shfl(rl, qrow);
    size_t base = ((size_t)(b * 2048 + q0w + qrow)) * 1024 + hh * 64 + lo;
    Ao[base]      = f2bf(o0[r] * s);
    Ao[base + 32] = f2bf(o1[r] * s);
  }
}

// ---------------- launcher ----------------
extern "C" void kernel_launch(void* const* d_in, const int* in_sizes, int n_in,
                              void* d_out, int out_size, void* d_ws, size_t ws_size,
                              hipStream_t stream) {
  const float* x      = (const float*)d_in[0];
  const float* W_qkv  = (const float*)d_in[1];
  const float* b_qkv  = (const float*)d_in[2];
  const float* W_proj = (const float*)d_in[3];
  const float* b_proj = (const float*)d_in[4];
  float* out = (float*)d_out;

  char* ws = (char*)d_ws;
  const size_t MB = 1u << 20;
  unsigned short* xb     = (unsigned short*)(ws);            // 8 MB (reused as attn out)
  unsigned short* WqkvT  = (unsigned short*)(ws + 8 * MB);   // 6 MB
  unsigned short* WprojT = (unsigned short*)(ws + 14 * MB);  // 2 MB
  unsigned short* Qb     = (unsigned short*)(ws + 16 * MB);  // 8 MB
  unsigned short* Kb     = (unsigned short*)(ws + 24 * MB);  // 8 MB
  unsigned short* Vt     = (unsigned short*)(ws + 32 * MB);  // 8 MB
  unsigned short* attn   = xb;                               // alias: xb dead after QKV GEMM

  cvt_x<<<2048, 256, 0, stream>>>(x, xb);
  transpose_cvt<<<dim3(96, 32), 256, 0, stream>>>(W_qkv, WqkvT, 1024, 3072);
  transpose_cvt<<<dim3(32, 32), 256, 0, stream>>>(W_proj, WprojT, 1024, 1024);
  gemm_bt<0><<<768, 256, 0, stream>>>(xb, WqkvT, b_qkv, 24, Qb, Kb, Vt, nullptr);
  attn_fwd<<<512, 256, 0, stream>>>(Qb, Kb, Vt, attn);
  gemm_bt<1><<<256, 256, 0, stream>>>(attn, WprojT, b_proj, 8, nullptr, nullptr, nullptr, out);
}